// Round 4
// baseline (215.896 us; speedup 1.0000x reference)
//
#include <hip/hip_runtime.h>
#include <stdint.h>

#define NROWS 8192
#define DIM   2048
#define MARGIN 2.0f

// ---- 256x256 8-phase tile kernel geometry ----
#define BT2     256
#define BK2     64
#define NKT     (DIM / BK2)              // 32 K-tiles
#define NT2     (NROWS / BT2)            // 32 tile-rows
#define NTILES2 (NT2 * (NT2 + 1) / 2)    // 528 upper-tri tiles
#define ABUF_EL 16384                    // 256*64 elements (A region per buffer)
#define BUF_EL  32768                    // A + B regions per buffer
#define HALF_EL 8192                     // 128*64 elements per half-tile
#define NSPLIT  16                       // tiles split into main+sliver
#define KSPLIT  30                       // main does K-tiles [0,30), sliver [30,32)

typedef __attribute__((ext_vector_type(8))) short short8;   // 8 bf16
typedef __attribute__((ext_vector_type(4))) float floatx4;  // C/D frag

__device__ __forceinline__ ushort f2bf(float x) {
    uint32_t u = __float_as_uint(x);
    uint32_t r = u + 0x7fffu + ((u >> 16) & 1u);   // RNE
    return (ushort)(r >> 16);
}
__device__ __forceinline__ float bf2f(ushort b) {
    return __uint_as_float(((uint32_t)b) << 16);
}

// triangular decode (ti <= tj): off(r) = r*NT2 - r(r-1)/2
__device__ __forceinline__ void decode_tile(int bid, int* ti, int* tj) {
    float fn = (float)NT2 + 0.5f;
    int r = (int)(fn - sqrtf(fn * fn - 2.0f * (float)bid));
    if (r < 0) r = 0;
    if (r >= NT2) r = NT2 - 1;
    while ((r + 1) * NT2 - ((r + 1) * r) / 2 <= bid) ++r;
    while (r * NT2 - (r * (r - 1)) / 2 > bid) --r;
    *ti = r;
    *tj = r + (bid - (r * NT2 - (r * (r - 1)) / 2));
}

// ---------------- kernel 1: fp32 -> bf16 cast + row sum of squares ----------
__global__ __launch_bounds__(256) void prep_kernel(const float* __restrict__ p,
                                                   ushort* __restrict__ pb,
                                                   float* __restrict__ sq) {
    int row = blockIdx.x;
    int t = threadIdx.x;
    const float4* prow = (const float4*)(p + (size_t)row * DIM);
    ushort* brow = pb + (size_t)row * DIM;
    float s = 0.f;
#pragma unroll
    for (int h = 0; h < 2; ++h) {
        int idx = h * 256 + t;
        float4 v = prow[idx];
        ushort4 o;
        o.x = f2bf(v.x); o.y = f2bf(v.y); o.z = f2bf(v.z); o.w = f2bf(v.w);
        float a = bf2f(o.x), b = bf2f(o.y), c = bf2f(o.z), d = bf2f(o.w);
        s += a * a + b * b + c * c + d * d;   // sumsq of ROUNDED values
        *(ushort4*)(brow + idx * 4) = o;
    }
#pragma unroll
    for (int o = 32; o > 0; o >>= 1) s += __shfl_down(s, o, 64);
    __shared__ float wsums[4];
    int lane = t & 63, wvv = t >> 6;
    if (lane == 0) wsums[wvv] = s;
    __syncthreads();
    if (t == 0) sq[row] = wsums[0] + wsums[1] + wsums[2] + wsums[3];
}

// ---------------- half-tile stage: global -> LDS (linear dest, pre-swizzled src)
// which: 0 = A half0, 1 = A half1, 2 = B half0, 3 = B half1, for K-tile t.
// t >= kend clamps to t-2: same buffer/region (parity preserved), data dead;
// the write window chosen for phase placement is identical, so still race-free.
__device__ __forceinline__ void stage_ht(const ushort* __restrict__ pb,
                                         ushort* lds, int t, int which,
                                         int ibase, int jbase, int tid, int kend) {
    if (t >= kend) t -= 2;
    const int h = which & 1;
    const int row0 = ((which >= 2) ? jbase : ibase) + h * 128;
    const ushort* g0 = pb + (size_t)row0 * DIM + t * BK2;
    ushort* l0 = lds + (t & 1) * BUF_EL + ((which >= 2) ? ABUF_EL : 0) + h * HALF_EL;
#pragma unroll
    for (int r = 0; r < 2; ++r) {
        int row = r * 64 + (tid >> 3);                 // row within half-tile
        int c8 = (tid & 7) ^ ((tid >> 3) & 7);         // pre-swizzled col slot
        const ushort* g = g0 + (size_t)row * DIM + c8 * 8;
        ushort* l = l0 + r * 4096 + (tid >> 6) * 512;  // wave-uniform base (+lane*16B HW)
        __builtin_amdgcn_global_load_lds(
            (const __attribute__((address_space(1))) uint32_t*)g,
            (__attribute__((address_space(3))) uint32_t*)l, 16, 0, 0);
    }
}

#define BARF()   do { __builtin_amdgcn_s_barrier(); \
                      asm volatile("" ::: "memory"); } while (0)
#define WAITL()  asm volatile("s_waitcnt lgkmcnt(0)" ::: "memory")
#define WAITV8() asm volatile("s_waitcnt vmcnt(8)" ::: "memory")
#define WAITV0() asm volatile("s_waitcnt vmcnt(0)" ::: "memory")
#define PRIO1()  __builtin_amdgcn_s_setprio(1)
#define PRIO0()  __builtin_amdgcn_s_setprio(0)

// swizzled ds_read of 16B fragments: row-major [*][64], col8 ^= (row&7) = (lane&7)
#define READ_A(AB, MH)                                                         \
    _Pragma("unroll") for (int m = 0; m < 4; ++m)                              \
    _Pragma("unroll") for (int k = 0; k < 2; ++k)                              \
        afr[m][k] = *(const short8*)&(AB)[                                     \
            (wr * 128 + ((MH) * 4 + m) * 16 + (lane & 15)) * 64 +              \
            (((k * 4 + (lane >> 4)) ^ (lane & 7)) * 8)];

#define READ_B(BB, NH)                                                         \
    _Pragma("unroll") for (int n = 0; n < 2; ++n)                              \
    _Pragma("unroll") for (int k = 0; k < 2; ++k)                              \
        bfr[(NH) * 2 + n][k] = *(const short8*)&(BB)[                          \
            (wc * 64 + ((NH) * 2 + n) * 16 + (lane & 15)) * 64 +               \
            (((k * 4 + (lane >> 4)) ^ (lane & 7)) * 8)];

#define MFMA_Q(MH, NH)                                                         \
    _Pragma("unroll") for (int m = 0; m < 4; ++m)                              \
    _Pragma("unroll") for (int n = 0; n < 2; ++n)                              \
    _Pragma("unroll") for (int k = 0; k < 2; ++k)                              \
        acc[(MH) * 4 + m][(NH) * 2 + n] =                                      \
            __builtin_amdgcn_mfma_f32_16x16x32_bf16(                           \
                afr[m][k], bfr[(NH) * 2 + n][k],                               \
                acc[(MH) * 4 + m][(NH) * 2 + n], 0, 0, 0);

// One K-tile = 4 phases. All stages for tile T+2 issue in P3/P4:
//   P3: B0,B1(T+2)->buf (safe: ALL B reads of buf close at end-P2 barrier)
//   P4: A0,A1(T+2)->buf (safe: ALL A reads of buf close at end-P3 barrier)
// Boundary s_waitcnt vmcnt(8): tile T+1's 8 loads retire (in-order count),
// tile T+2's 8 stay in flight. Never vmcnt(0) in-loop.
#define TILE_STEP(T, BUF)                                                      \
    {                                                                          \
        const ushort* Ab = &lds[(BUF) * BUF_EL];                               \
        const ushort* Bb = &lds[(BUF) * BUF_EL + ABUF_EL];                     \
        /* P1: Q(0,0) — 12 ds_reads, no stage */                               \
        READ_A(Ab, 0);                                                         \
        READ_B(Bb, 0);                                                         \
        BARF(); WAITL();                                                       \
        PRIO1(); MFMA_Q(0, 0); PRIO0();                                        \
        BARF();                                                                \
        /* P2: Q(0,1) — 4 ds_reads */                                          \
        READ_B(Bb, 1);                                                         \
        BARF(); WAITL();                                                       \
        PRIO1(); MFMA_Q(0, 1); PRIO0();                                        \
        BARF();                                                                \
        /* P3: Q(1,0) — 8 ds_reads + stage B(T+2) */                           \
        READ_A(Ab, 1);                                                         \
        stage_ht(pb, lds, (T) + 2, 2, ibase, jbase, tid, kend);                \
        stage_ht(pb, lds, (T) + 2, 3, ibase, jbase, tid, kend);                \
        BARF(); WAITL();                                                       \
        PRIO1(); MFMA_Q(1, 0); PRIO0();                                        \
        BARF();                                                                \
        /* P4: Q(1,1) — stage A(T+2), counted vmcnt at tile boundary */        \
        stage_ht(pb, lds, (T) + 2, 0, ibase, jbase, tid, kend);                \
        stage_ht(pb, lds, (T) + 2, 1, ibase, jbase, tid, kend);                \
        PRIO1(); MFMA_Q(1, 1); PRIO0();                                        \
        WAITV8();                                                              \
        BARF();                                                                \
    }

// ---------------- kernel 2: 256² 8-phase triangular Gram + fused loss -------
// Grid = NSPLIT slivers (block 0..15) + 528 tiles. 16 tiles (bid%33==1, all
// off-diagonal) are split by K: main [0,KSPLIT), sliver [KSPLIT,NKT). Split
// blocks store partial Gram to ws; combine_kernel finishes them.
__global__ __launch_bounds__(512) void tile2_kernel(
    const ushort* __restrict__ pb, const float* __restrict__ sq,
    const int* __restrict__ gt, double* __restrict__ accum,
    float* __restrict__ partials) {

    __shared__ ushort lds[2 * BUF_EL];   // 128 KiB: 2 x (A[256][64] + B[256][64])
    __shared__ float wsum[8];

    int bx = (int)blockIdx.x;
    int bid, kbeg, kend, slot = 0;
    bool do_loss;
    bool sliver = (bx < NSPLIT);
    if (sliver) {
        slot = bx; bid = bx * 33 + 1;
        kbeg = KSPLIT; kend = NKT; do_loss = false;
    } else {
        int phys = bx - NSPLIT;
        bid = (phys & 7) * 66 + (phys >> 3);   // bijective XCD swizzle (528=8*66)
        if (bid % 33 == 1) { slot = bid / 33; kbeg = 0; kend = KSPLIT; do_loss = false; }
        else               { kbeg = 0; kend = NKT;    do_loss = true; }
    }

    int ti, tj;
    decode_tile(bid, &ti, &tj);

    const int tid = threadIdx.x;
    const int lane = tid & 63;
    const int wv = tid >> 6;
    const int wr = wv >> 2;   // 0..1 : wave row (128 rows each)
    const int wc = wv & 3;    // 0..3 : wave col (64 cols each)
    const int ibase = ti * BT2;
    const int jbase = tj * BT2;

    floatx4 acc[8][4] = {};
    short8 afr[4][2];
    short8 bfr[4][2];

    // prologue: tile kbeg {all 4 halves}, tile kbeg+1 {all 4}; vmcnt(8) ->
    // tile kbeg resident, tile kbeg+1's 8 loads in flight (steady invariant).
    stage_ht(pb, lds, kbeg, 2, ibase, jbase, tid, kend);
    stage_ht(pb, lds, kbeg, 3, ibase, jbase, tid, kend);
    stage_ht(pb, lds, kbeg, 0, ibase, jbase, tid, kend);
    stage_ht(pb, lds, kbeg, 1, ibase, jbase, tid, kend);
    stage_ht(pb, lds, kbeg + 1, 2, ibase, jbase, tid, kend);
    stage_ht(pb, lds, kbeg + 1, 3, ibase, jbase, tid, kend);
    stage_ht(pb, lds, kbeg + 1, 0, ibase, jbase, tid, kend);
    stage_ht(pb, lds, kbeg + 1, 1, ibase, jbase, tid, kend);
    WAITV8();
    BARF();

    for (int s0 = kbeg; s0 < kend; s0 += 2) {   // kbeg even, (kend-kbeg) even
        TILE_STEP(s0, ((s0) & 1));
        TILE_STEP(s0 + 1, ((s0 + 1) & 1));
    }
    WAITV0();   // drain dead tail stages before exit
    BARF();

    if (do_loss) {
        // fused epilogue: d2 -> contrastive term -> weighted partial sum
        const float invd = 1.0f / (float)DIM;
        float lsum = 0.f;
        int j0 = jbase + wc * 64 + (lane & 15);
        float sqj[4]; int gj[4];
#pragma unroll
        for (int n = 0; n < 4; ++n) { int j = j0 + n * 16; sqj[n] = sq[j]; gj[n] = gt[j]; }
        const float wb = (ti != tj) ? 2.0f : 1.0f;
#pragma unroll
        for (int mi = 0; mi < 8; ++mi) {
#pragma unroll
            for (int rr = 0; rr < 4; ++rr) {
                int i = ibase + wr * 128 + mi * 16 + (lane >> 4) * 4 + rr;
                float sqi = sq[i];
                int gi = gt[i];
#pragma unroll
                for (int n = 0; n < 4; ++n) {
                    int j = j0 + n * 16;
                    float d2 = fmaxf(sqi + sqj[n] - 2.0f * acc[mi][n][rr], 0.0f) * invd;
                    float term = (gi == gj[n]) ? d2 : fmaxf(MARGIN - d2, 0.0f);
                    float w = wb;
                    if (ti == tj && i == j) w = 2.0f;   // triu diagonal counted once*2
                    lsum += w * term;
                }
            }
        }
#pragma unroll
        for (int o = 32; o > 0; o >>= 1) lsum += __shfl_down(lsum, o, 64);
        if (lane == 0) wsum[wv] = lsum;
        __syncthreads();
        if (tid == 0) {
            float s = 0.f;
#pragma unroll
            for (int w = 0; w < 8; ++w) s += wsum[w];
            atomicAdd(accum, (double)s);
        }
    } else {
        // store partial Gram tile, column-major [j][i], float4 over i (rr dim)
        float* base = partials + ((size_t)slot + (sliver ? NSPLIT : 0)) * (BT2 * BT2);
        int i0 = wr * 128 + (lane >> 4) * 4;
        int jl0 = wc * 64 + (lane & 15);
#pragma unroll
        for (int mi = 0; mi < 8; ++mi)
#pragma unroll
            for (int n = 0; n < 4; ++n)
                *(floatx4*)&base[(size_t)(jl0 + n * 16) * BT2 + i0 + mi * 16] = acc[mi][n];
    }
}

// ---------------- kernel 2b: combine split-tile partials + loss terms -------
__global__ __launch_bounds__(256) void combine_kernel(
    const float* __restrict__ partials, const float* __restrict__ sq,
    const int* __restrict__ gt, double* __restrict__ accum) {
    int b = (int)blockIdx.x;           // 64 blocks: 16 slots x 4 quarters
    int slot = b >> 2, q = b & 3;
    int bid = slot * 33 + 1;           // all off-diagonal -> weight 2
    int ti, tj;
    decode_tile(bid, &ti, &tj);
    const float* pA = partials + (size_t)slot * (BT2 * BT2);
    const float* pB = partials + (size_t)(slot + NSPLIT) * (BT2 * BT2);
    const float invd = 1.0f / (float)DIM;
    float lsum = 0.f;
    for (int e = q * 16384 + (int)threadIdx.x; e < (q + 1) * 16384; e += 256) {
        int j = e >> 8, i = e & 255;                  // column-major storage
        float dot = pA[e] + pB[e];
        int ig = ti * BT2 + i, jg = tj * BT2 + j;
        float d2 = fmaxf(sq[ig] + sq[jg] - 2.0f * dot, 0.0f) * invd;
        float term = (gt[ig] == gt[jg]) ? d2 : fmaxf(MARGIN - d2, 0.0f);
        lsum += 2.0f * term;
    }
#pragma unroll
    for (int o = 32; o > 0; o >>= 1) lsum += __shfl_down(lsum, o, 64);
    __shared__ float ws4[4];
    if ((threadIdx.x & 63) == 0) ws4[threadIdx.x >> 6] = lsum;
    __syncthreads();
    if (threadIdx.x == 0)
        atomicAdd(accum, (double)(ws4[0] + ws4[1] + ws4[2] + ws4[3]));
}

// ---------------- kernel 3: finalize ----------------------------------------
__global__ void finalize_kernel(const double* __restrict__ accum,
                                float* __restrict__ out) {
    if (threadIdx.x == 0)
        out[0] = (float)(accum[0] * (1.0 / ((double)NROWS * (double)(NROWS - 1))));
}

extern "C" void kernel_launch(void* const* d_in, const int* in_sizes, int n_in,
                              void* d_out, int out_size, void* d_ws, size_t ws_size,
                              hipStream_t stream) {
    (void)in_sizes; (void)n_in; (void)out_size; (void)ws_size;
    const float* p = (const float*)d_in[0];
    const int* gt = (const int*)d_in[1];
    float* out = (float*)d_out;

    // ws layout: pb 32MB | sq 32KB | accum 8B (pad 256) | partials 8MB
    ushort* pb = (ushort*)d_ws;
    size_t off = (size_t)NROWS * DIM * 2;               // 33,554,432
    float* sq = (float*)((char*)d_ws + off);
    off += (size_t)NROWS * sizeof(float);               // +32 KB
    double* accum = (double*)((char*)d_ws + off);
    off += 256;
    float* partials = (float*)((char*)d_ws + off);      // 2*16*256*256*4 = 8 MB

    (void)hipMemsetAsync(accum, 0, sizeof(double), stream);
    prep_kernel<<<NROWS, 256, 0, stream>>>(p, pb, sq);
    tile2_kernel<<<NTILES2 + NSPLIT, 512, 0, stream>>>(pb, sq, gt, accum, partials);
    combine_kernel<<<4 * NSPLIT, 256, 0, stream>>>(partials, sq, gt, accum);
    finalize_kernel<<<1, 64, 0, stream>>>(accum, out);
}